// Round 1
// baseline (1152.362 us; speedup 1.0000x reference)
//
#include <hip/hip_runtime.h>
#include <stdint.h>

// Bahdanau attention, MI355X.
// K1a: W1 [2048][512] f32 -> W1T bf16 [512][2048] (B^T layout for MFMA b128 frag reads)
// K1b: proj_h[b][a] = hidden[b]@W2 + b2
// K2 : score[m] = sum_a V[a]*tanh(feat[m]@W1[:,a] + b1[a] + proj_h[b][a])   (bf16 MFMA GEMM, fused epilogue)
// K3 : softmax over L per batch -> weights output; zeroes context
// K4 : context[b][e] = sum_l w[b][l]*feat[b][l][e]  (atomicAdd partials)
// bv cancels in softmax and score is not an output -> unused.

typedef float  f32x4 __attribute__((ext_vector_type(4)));
typedef short  s16x8 __attribute__((ext_vector_type(8)));
typedef unsigned short u16x4 __attribute__((ext_vector_type(4)));

#define AS_GLB __attribute__((address_space(1)))
#define AS_LDS __attribute__((address_space(3)))

__device__ __forceinline__ unsigned short f2bf(float f) {
    unsigned int u = __float_as_uint(f);
    u += 0x7fffu + ((u >> 16) & 1u);          // RNE
    return (unsigned short)(u >> 16);
}

// ---------- K1a: tiled transpose + bf16 cast of W1 ----------
__global__ __launch_bounds__(256) void k_w1t(const float* __restrict__ W1,
                                             unsigned short* __restrict__ w1t) {
    __shared__ float tile[64][65];
    const int k0 = blockIdx.x * 64;
    const int n0 = blockIdx.y * 64;
    const int t = threadIdx.x, ty = t >> 6, tx = t & 63;
    #pragma unroll
    for (int i = ty; i < 64; i += 4)
        tile[i][tx] = W1[(size_t)(k0 + i) * 512 + n0 + tx];
    __syncthreads();
    #pragma unroll
    for (int i = ty; i < 64; i += 4)
        w1t[(size_t)(n0 + i) * 2048 + k0 + tx] = f2bf(tile[tx][i]);
}

// ---------- K1b: proj_h = hidden @ W2 + b2 ----------
__global__ __launch_bounds__(256) void k_projh(const float* __restrict__ hs,
                                               const float* __restrict__ W2,
                                               const float* __restrict__ b2,
                                               float* __restrict__ ph) {
    __shared__ float h[512];
    const int b = blockIdx.x, t = threadIdx.x;
    h[t]       = hs[b * 512 + t];
    h[t + 256] = hs[b * 512 + t + 256];
    __syncthreads();
    float a0 = b2[t], a1 = b2[t + 256];
    for (int d = 0; d < 512; ++d) {
        const float hv = h[d];
        a0 += hv * W2[d * 512 + t];
        a1 += hv * W2[d * 512 + t + 256];
    }
    ph[b * 512 + t]       = a0;
    ph[b * 512 + t + 256] = a1;
}

// ---------- K2: fused GEMM(bf16 MFMA) + tanh + V-dot -> score ----------
// grid 2048 (M/32), 256 threads = 4 waves; wave w owns cols [w*128, w*128+128)
__global__ __launch_bounds__(256) void k_score(const float* __restrict__ feat,
                                               const unsigned short* __restrict__ w1t,
                                               const float* __restrict__ b1,
                                               const float* __restrict__ ph,
                                               const float* __restrict__ V,
                                               float* __restrict__ score) {
    __shared__ __align__(16) unsigned short As[32 * 32];    // [m][k] bf16
    __shared__ __align__(16) unsigned short Bs[512 * 32];   // [n][k] bf16
    __shared__ float red[4][32];

    const int tid  = threadIdx.x;
    const int wave = tid >> 6, lane = tid & 63;
    const int quad = lane >> 4, l15 = lane & 15;
    const int m0 = blockIdx.x * 32;
    const int bb = m0 >> 10;                                 // batch index (32 | 1024)

    const float* fptr = feat + (size_t)(m0 + (tid >> 3)) * 2048 + (tid & 7) * 4;
    const int a_lds_off = (tid >> 3) * 32 + (tid & 7) * 4;

    f32x4 acc[2][8];
    const f32x4 zero = {0.f, 0.f, 0.f, 0.f};
    #pragma unroll
    for (int i = 0; i < 2; ++i)
        #pragma unroll
        for (int j = 0; j < 8; ++j) acc[i][j] = zero;

    for (int ks = 0; ks < 64; ++ks) {
        const int k0 = ks * 32;
        const f32x4 av = *(const f32x4*)(fptr + k0);         // A global->reg (pre-barrier)
        __syncthreads();                                     // prior-iter LDS reads done
        u16x4 a4;
        a4.x = f2bf(av.x); a4.y = f2bf(av.y); a4.z = f2bf(av.z); a4.w = f2bf(av.w);
        *(u16x4*)(&As[a_lds_off]) = a4;                      // ds_write_b64
        #pragma unroll
        for (int it = 0; it < 8; ++it) {                     // B: global_load_lds x16B
            const int c = wave * 512 + it * 64 + lane;       // chunk id; LDS off = c*16
            const unsigned short* g = w1t + (size_t)(c >> 2) * 2048 + k0 + (c & 3) * 8;
            unsigned short* l = &Bs[(wave * 512 + it * 64) * 8];   // wave-uniform base
            __builtin_amdgcn_global_load_lds((const AS_GLB uint32_t*)g,
                                             (AS_LDS uint32_t*)l, 16, 0, 0);
        }
        __syncthreads();                                     // staging visible (vmcnt drain)

        s16x8 af[2], bf[8];
        #pragma unroll
        for (int i = 0; i < 2; ++i)
            af[i] = *(const s16x8*)(&As[(i * 16 + l15) * 32 + quad * 8]);
        #pragma unroll
        for (int j = 0; j < 8; ++j)
            bf[j] = *(const s16x8*)(&Bs[(wave * 128 + j * 16 + l15) * 32 + quad * 8]);
        #pragma unroll
        for (int i = 0; i < 2; ++i)
            #pragma unroll
            for (int j = 0; j < 8; ++j)
                acc[i][j] = __builtin_amdgcn_mfma_f32_16x16x32_bf16(af[i], bf[j], acc[i][j], 0, 0, 0);
    }

    // epilogue: ls[i][r] = sum over this lane's cols of V[n]*tanh(acc + b1[n] + ph[b][n])
    float ls[2][4] = {{0, 0, 0, 0}, {0, 0, 0, 0}};
    #pragma unroll
    for (int j = 0; j < 8; ++j) {
        const int n = wave * 128 + j * 16 + l15;
        const float bias = b1[n] + ph[bb * 512 + n];
        const float vj = V[n];
        #pragma unroll
        for (int i = 0; i < 2; ++i)
            #pragma unroll
            for (int r = 0; r < 4; ++r)
                ls[i][r] += vj * tanhf(acc[i][j][r] + bias);
    }
    #pragma unroll
    for (int m = 1; m < 16; m <<= 1)                         // reduce over col lanes
        #pragma unroll
        for (int i = 0; i < 2; ++i)
            #pragma unroll
            for (int r = 0; r < 4; ++r)
                ls[i][r] += __shfl_xor(ls[i][r], m, 64);
    if (l15 == 0) {
        #pragma unroll
        for (int i = 0; i < 2; ++i)
            #pragma unroll
            for (int r = 0; r < 4; ++r)
                red[wave][i * 16 + quad * 4 + r] = ls[i][r];
    }
    __syncthreads();
    if (tid < 32)
        score[m0 + tid] = red[0][tid] + red[1][tid] + red[2][tid] + red[3][tid];
}

// ---------- K3: softmax over L, write weights, zero context ----------
__global__ __launch_bounds__(256) void k_softmax(const float* __restrict__ score,
                                                 float* __restrict__ wout,
                                                 float* __restrict__ ctx) {
    __shared__ float sred[4];
    const int b = blockIdx.x, t = threadIdx.x;
    const int wave = t >> 6, lane = t & 63;
    float s[4];
    #pragma unroll
    for (int i = 0; i < 4; ++i) s[i] = score[b * 1024 + t + i * 256];
    float mx = fmaxf(fmaxf(s[0], s[1]), fmaxf(s[2], s[3]));
    #pragma unroll
    for (int m = 1; m < 64; m <<= 1) mx = fmaxf(mx, __shfl_xor(mx, m, 64));
    if (lane == 0) sred[wave] = mx;
    __syncthreads();
    mx = fmaxf(fmaxf(sred[0], sred[1]), fmaxf(sred[2], sred[3]));
    float e[4], sum = 0.f;
    #pragma unroll
    for (int i = 0; i < 4; ++i) { e[i] = __expf(s[i] - mx); sum += e[i]; }
    #pragma unroll
    for (int m = 1; m < 64; m <<= 1) sum += __shfl_xor(sum, m, 64);
    __syncthreads();
    if (lane == 0) sred[wave] = sum;
    __syncthreads();
    const float inv = 1.0f / (sred[0] + sred[1] + sred[2] + sred[3]);
    #pragma unroll
    for (int i = 0; i < 4; ++i) wout[b * 1024 + t + i * 256] = e[i] * inv;
    #pragma unroll
    for (int i = 0; i < 8; ++i) ctx[b * 2048 + t + i * 256] = 0.f;   // K4 accumulates
}

// ---------- K4: context = sum_l w*features ----------
// grid (64, 8): batch x L-chunk(128); 256 threads x 8 floats = 2048 cols
__global__ __launch_bounds__(256) void k_ctx(const float* __restrict__ feat,
                                             const float* __restrict__ wgt,
                                             float* __restrict__ ctx) {
    __shared__ float wl[128];
    const int b = blockIdx.x, lc = blockIdx.y, t = threadIdx.x;
    if (t < 128) wl[t] = wgt[b * 1024 + lc * 128 + t];
    __syncthreads();
    const float* fp = feat + ((size_t)b * 1024 + (size_t)lc * 128) * 2048 + t * 8;
    f32x4 a0 = {0.f, 0.f, 0.f, 0.f}, a1 = {0.f, 0.f, 0.f, 0.f};
    #pragma unroll 4
    for (int l = 0; l < 128; ++l) {
        const f32x4 f0 = *(const f32x4*)(fp + (size_t)l * 2048);
        const f32x4 f1 = *(const f32x4*)(fp + (size_t)l * 2048 + 4);
        const float w = wl[l];
        a0 += w * f0;
        a1 += w * f1;
    }
    float* cp = ctx + b * 2048 + t * 8;
    atomicAdd(cp + 0, a0.x); atomicAdd(cp + 1, a0.y);
    atomicAdd(cp + 2, a0.z); atomicAdd(cp + 3, a0.w);
    atomicAdd(cp + 4, a1.x); atomicAdd(cp + 5, a1.y);
    atomicAdd(cp + 6, a1.z); atomicAdd(cp + 7, a1.w);
}

extern "C" void kernel_launch(void* const* d_in, const int* in_sizes, int n_in,
                              void* d_out, int out_size, void* d_ws, size_t ws_size,
                              hipStream_t stream) {
    const float* feat = (const float*)d_in[0];   // [64][1024][2048]
    const float* hs   = (const float*)d_in[1];   // [64][512]
    const float* W1   = (const float*)d_in[2];   // [2048][512]
    const float* b1   = (const float*)d_in[3];   // [512]
    const float* W2   = (const float*)d_in[4];   // [512][512]
    const float* b2   = (const float*)d_in[5];   // [512]
    const float* V    = (const float*)d_in[6];   // [512]
    // d_in[7] = bv: cancels in softmax, score not an output -> unused

    unsigned short* w1t = (unsigned short*)d_ws;                               // 2 MiB
    float* ph    = (float*)((char*)d_ws + 2u * 1024 * 1024);                   // 128 KiB
    float* score = (float*)((char*)d_ws + 2u * 1024 * 1024 + 128u * 1024);     // 256 KiB

    float* ctx  = (float*)d_out;          // [64][2048]
    float* wout = ctx + 64 * 2048;        // [64][1024][1]

    k_w1t   <<<dim3(32, 8), 256, 0, stream>>>(W1, w1t);
    k_projh <<<64,          256, 0, stream>>>(hs, W2, b2, ph);
    k_score <<<2048,        256, 0, stream>>>(feat, w1t, b1, ph, V, score);
    k_softmax<<<64,         256, 0, stream>>>(score, wout, ctx);
    k_ctx   <<<dim3(64, 8), 256, 0, stream>>>(feat, wout, ctx);
}

// Round 2
// 925.961 us; speedup vs baseline: 1.2445x; 1.2445x over previous
//
#include <hip/hip_runtime.h>
#include <stdint.h>

// Bahdanau attention, MI355X. Round 2.
// k_score: BM=64 x BN=512(full) x BK=32 bf16-MFMA GEMM, XOR-swizzled LDS
//          (conflict-free b128 frag reads), A-prefetch issued after the drain
//          barrier so its HBM latency ages through the MFMA phase.
// k_ctx:   partial-buffer + reduce (no atomics) when ws allows; atomic fallback.

typedef float  f32x4 __attribute__((ext_vector_type(4)));
typedef short  s16x8 __attribute__((ext_vector_type(8)));
typedef unsigned short u16x8 __attribute__((ext_vector_type(8)));

#define AS_GLB __attribute__((address_space(1)))
#define AS_LDS __attribute__((address_space(3)))

__device__ __forceinline__ unsigned short f2bf(float f) {
    unsigned int u = __float_as_uint(f);
    u += 0x7fffu + ((u >> 16) & 1u);          // RNE
    return (unsigned short)(u >> 16);
}

__device__ __forceinline__ float fast_tanh(float x) {
    // 1 - 2/(e^{2x}+1); saturates correctly at +/-inf, ~1e-6 abs error
    return 1.0f - 2.0f / (__expf(2.0f * x) + 1.0f);
}

// ---------- K1a: tiled transpose + bf16 cast of W1 -> w1t[n][k] ----------
__global__ __launch_bounds__(256) void k_w1t(const float* __restrict__ W1,
                                             unsigned short* __restrict__ w1t) {
    __shared__ float tile[64][65];
    const int k0 = blockIdx.x * 64;
    const int n0 = blockIdx.y * 64;
    const int t = threadIdx.x, ty = t >> 6, tx = t & 63;
    #pragma unroll
    for (int i = ty; i < 64; i += 4)
        tile[i][tx] = W1[(size_t)(k0 + i) * 512 + n0 + tx];
    __syncthreads();
    #pragma unroll
    for (int i = ty; i < 64; i += 4)
        w1t[(size_t)(n0 + i) * 2048 + k0 + tx] = f2bf(tile[tx][i]);
}

// ---------- K1b: proj_h = hidden @ W2 + b2 (grid 64x4) ----------
__global__ __launch_bounds__(256) void k_projh(const float* __restrict__ hs,
                                               const float* __restrict__ W2,
                                               const float* __restrict__ b2,
                                               float* __restrict__ ph) {
    __shared__ float hsm[512];
    __shared__ float part[256];
    const int b = blockIdx.x, c0 = blockIdx.y * 128, t = threadIdx.x;
    hsm[t]       = hs[b * 512 + t];
    hsm[t + 256] = hs[b * 512 + t + 256];
    __syncthreads();
    const int j = c0 + (t & 127), half = t >> 7;
    float s = 0.f;
    const float* wp = W2 + (size_t)(half * 256) * 512 + j;
    const float* hp = hsm + half * 256;
    #pragma unroll 8
    for (int i = 0; i < 256; ++i) s += hp[i] * wp[(size_t)i * 512];
    part[t] = s;
    __syncthreads();
    if (t < 128) ph[b * 512 + j] = part[t] + part[t + 128] + b2[j];
}

// ---------- K2: fused GEMM + tanh + V-dot -> score ----------
// grid 1024 (M/64), 256 threads = 4 waves; wave w owns cols [w*128, w*128+128)
// LDS chunk layout (16B chunks): slot(row, c) = row*4 + (c ^ ((row>>1)&3))
__global__ __launch_bounds__(256, 2) void k_score(const float* __restrict__ feat,
                                                  const unsigned short* __restrict__ w1t,
                                                  const float* __restrict__ b1,
                                                  const float* __restrict__ ph,
                                                  const float* __restrict__ V,
                                                  float* __restrict__ score) {
    __shared__ __align__(16) unsigned short As[64 * 32];    // 4 KiB, swizzled
    __shared__ __align__(16) unsigned short Bs[512 * 32];   // 32 KiB, swizzled
    __shared__ float red[4][64];

    const int tid  = threadIdx.x;
    const int wave = tid >> 6, lane = tid & 63;
    const int quad = lane >> 4, l15 = lane & 15;
    const int m0 = blockIdx.x * 64;
    const int bb = m0 >> 10;                                 // batch (64 rows never cross batch)

    // A staging: 256 chunks (m:64 x c:4), one per thread
    const int am = tid >> 2, ac = tid & 3;
    const float* aptr = feat + (size_t)(m0 + am) * 2048 + ac * 8;
    const int asl = (am * 4 + (ac ^ ((am >> 1) & 3))) * 8;   // ushort offset

    // B staging: 8 reps/thread; per-lane constants
    const int bn0 = wave * 128 + (lane >> 2);                // n for rep 0
    const int bc  = (lane & 3) ^ ((lane >> 3) & 3);          // k-chunk (constant)
    const unsigned short* bptr = w1t + (size_t)bn0 * 2048 + bc * 8;

    f32x4 acc[4][8];
    const f32x4 zero = {0.f, 0.f, 0.f, 0.f};
    #pragma unroll
    for (int i = 0; i < 4; ++i)
        #pragma unroll
        for (int j = 0; j < 8; ++j) acc[i][j] = zero;

    f32x4 a0 = *(const f32x4*)aptr;                          // prefetch ks=0
    f32x4 a1 = *(const f32x4*)(aptr + 4);

    for (int ks = 0; ks < 64; ++ks) {
        __syncthreads();                                     // prior-iter LDS reads done
        u16x8 aw;
        aw[0] = f2bf(a0.x); aw[1] = f2bf(a0.y); aw[2] = f2bf(a0.z); aw[3] = f2bf(a0.w);
        aw[4] = f2bf(a1.x); aw[5] = f2bf(a1.y); aw[6] = f2bf(a1.z); aw[7] = f2bf(a1.w);
        *(u16x8*)(&As[asl]) = aw;                            // ds_write_b128
        const unsigned short* g = bptr + ks * 32;
        #pragma unroll
        for (int r = 0; r < 8; ++r) {                        // 2048 chunks / 256 thr
            __builtin_amdgcn_global_load_lds((const AS_GLB uint32_t*)(g + (size_t)r * 32768),
                                             (AS_LDS uint32_t*)(&Bs[(wave * 512 + r * 64) * 8]),
                                             16, 0, 0);
        }
        __syncthreads();                                     // staging drained (vmcnt 0)

        if (ks < 63) {                                       // prefetch next A AFTER the
            const float* ap = aptr + (ks + 1) * 32;          // drain -> latency ages
            a0 = *(const f32x4*)ap;                          // through the MFMA phase
            a1 = *(const f32x4*)(ap + 4);
        }

        s16x8 af[4], bf[8];
        #pragma unroll
        for (int i = 0; i < 4; ++i) {
            const int m = i * 16 + l15;
            af[i] = *(const s16x8*)(&As[(m * 4 + (quad ^ ((m >> 1) & 3))) * 8]);
        }
        #pragma unroll
        for (int j = 0; j < 8; ++j) {
            const int n = wave * 128 + j * 16 + l15;
            bf[j] = *(const s16x8*)(&Bs[(n * 4 + (quad ^ ((n >> 1) & 3))) * 8]);
        }
        #pragma unroll
        for (int i = 0; i < 4; ++i)
            #pragma unroll
            for (int j = 0; j < 8; ++j)
                acc[i][j] = __builtin_amdgcn_mfma_f32_16x16x32_bf16(af[i], bf[j], acc[i][j], 0, 0, 0);
    }

    // epilogue: score rows m = i*16 + quad*4 + r, cols n = wave*128 + j*16 + l15
    float ls[4][4];
    #pragma unroll
    for (int i = 0; i < 4; ++i)
        #pragma unroll
        for (int r = 0; r < 4; ++r) ls[i][r] = 0.f;
    #pragma unroll
    for (int j = 0; j < 8; ++j) {
        const int n = wave * 128 + j * 16 + l15;
        const float bias = b1[n] + ph[bb * 512 + n];
        const float vj = V[n];
        #pragma unroll
        for (int i = 0; i < 4; ++i)
            #pragma unroll
            for (int r = 0; r < 4; ++r)
                ls[i][r] += vj * fast_tanh(acc[i][j][r] + bias);
    }
    #pragma unroll
    for (int m = 1; m < 16; m <<= 1)
        #pragma unroll
        for (int i = 0; i < 4; ++i)
            #pragma unroll
            for (int r = 0; r < 4; ++r)
                ls[i][r] += __shfl_xor(ls[i][r], m, 64);
    if (l15 == 0) {
        #pragma unroll
        for (int i = 0; i < 4; ++i)
            #pragma unroll
            for (int r = 0; r < 4; ++r)
                red[wave][i * 16 + quad * 4 + r] = ls[i][r];
    }
    __syncthreads();
    if (tid < 64)
        score[m0 + tid] = red[0][tid] + red[1][tid] + red[2][tid] + red[3][tid];
}

// ---------- K3: softmax over L ----------
__global__ __launch_bounds__(256) void k_softmax(const float* __restrict__ score,
                                                 float* __restrict__ wout,
                                                 float* __restrict__ ctx,
                                                 int zero_ctx) {
    __shared__ float sred[4];
    const int b = blockIdx.x, t = threadIdx.x;
    const int wave = t >> 6, lane = t & 63;
    float s[4];
    #pragma unroll
    for (int i = 0; i < 4; ++i) s[i] = score[b * 1024 + t + i * 256];
    float mx = fmaxf(fmaxf(s[0], s[1]), fmaxf(s[2], s[3]));
    #pragma unroll
    for (int m = 1; m < 64; m <<= 1) mx = fmaxf(mx, __shfl_xor(mx, m, 64));
    if (lane == 0) sred[wave] = mx;
    __syncthreads();
    mx = fmaxf(fmaxf(sred[0], sred[1]), fmaxf(sred[2], sred[3]));
    float e[4], sum = 0.f;
    #pragma unroll
    for (int i = 0; i < 4; ++i) { e[i] = __expf(s[i] - mx); sum += e[i]; }
    #pragma unroll
    for (int m = 1; m < 64; m <<= 1) sum += __shfl_xor(sum, m, 64);
    __syncthreads();
    if (lane == 0) sred[wave] = sum;
    __syncthreads();
    const float inv = 1.0f / (sred[0] + sred[1] + sred[2] + sred[3]);
    #pragma unroll
    for (int i = 0; i < 4; ++i) wout[b * 1024 + t + i * 256] = e[i] * inv;
    if (zero_ctx) {
        #pragma unroll
        for (int i = 0; i < 8; ++i) ctx[b * 2048 + t + i * 256] = 0.f;
    }
}

// ---------- K4: context partials (no atomics) ----------
__global__ __launch_bounds__(256) void k_ctx_part(const float* __restrict__ feat,
                                                  const float* __restrict__ wgt,
                                                  float* __restrict__ part) {
    __shared__ float wl[128];
    const int b = blockIdx.x, lc = blockIdx.y, t = threadIdx.x;
    if (t < 128) wl[t] = wgt[b * 1024 + lc * 128 + t];
    __syncthreads();
    const float* fp = feat + ((size_t)b * 1024 + (size_t)lc * 128) * 2048 + t * 8;
    f32x4 a0 = {0.f, 0.f, 0.f, 0.f}, a1 = {0.f, 0.f, 0.f, 0.f};
    #pragma unroll 4
    for (int l = 0; l < 128; ++l) {
        const f32x4 f0 = *(const f32x4*)(fp + (size_t)l * 2048);
        const f32x4 f1 = *(const f32x4*)(fp + (size_t)l * 2048 + 4);
        const float w = wl[l];
        a0 += w * f0;
        a1 += w * f1;
    }
    float* pp = part + ((size_t)(b * 8 + lc)) * 2048 + t * 8;
    *(f32x4*)pp = a0;
    *(f32x4*)(pp + 4) = a1;
}

__global__ __launch_bounds__(256) void k_ctx_red(const float* __restrict__ part,
                                                 float* __restrict__ ctx) {
    const int b = blockIdx.x, t = threadIdx.x;
    const float* pp = part + (size_t)b * 8 * 2048 + t * 8;
    f32x4 s0 = {0.f, 0.f, 0.f, 0.f}, s1 = {0.f, 0.f, 0.f, 0.f};
    #pragma unroll
    for (int r = 0; r < 8; ++r) {
        s0 += *(const f32x4*)(pp + (size_t)r * 2048);
        s1 += *(const f32x4*)(pp + (size_t)r * 2048 + 4);
    }
    float* cp = ctx + b * 2048 + t * 8;
    *(f32x4*)cp = s0;
    *(f32x4*)(cp + 4) = s1;
}

// ---------- K4 fallback: atomics (if ws too small for partials) ----------
__global__ __launch_bounds__(256) void k_ctx_atomic(const float* __restrict__ feat,
                                                    const float* __restrict__ wgt,
                                                    float* __restrict__ ctx) {
    __shared__ float wl[128];
    const int b = blockIdx.x, lc = blockIdx.y, t = threadIdx.x;
    if (t < 128) wl[t] = wgt[b * 1024 + lc * 128 + t];
    __syncthreads();
    const float* fp = feat + ((size_t)b * 1024 + (size_t)lc * 128) * 2048 + t * 8;
    f32x4 a0 = {0.f, 0.f, 0.f, 0.f}, a1 = {0.f, 0.f, 0.f, 0.f};
    #pragma unroll 4
    for (int l = 0; l < 128; ++l) {
        const f32x4 f0 = *(const f32x4*)(fp + (size_t)l * 2048);
        const f32x4 f1 = *(const f32x4*)(fp + (size_t)l * 2048 + 4);
        const float w = wl[l];
        a0 += w * f0;
        a1 += w * f1;
    }
    float* cp = ctx + b * 2048 + t * 8;
    atomicAdd(cp + 0, a0.x); atomicAdd(cp + 1, a0.y);
    atomicAdd(cp + 2, a0.z); atomicAdd(cp + 3, a0.w);
    atomicAdd(cp + 4, a1.x); atomicAdd(cp + 5, a1.y);
    atomicAdd(cp + 6, a1.z); atomicAdd(cp + 7, a1.w);
}

extern "C" void kernel_launch(void* const* d_in, const int* in_sizes, int n_in,
                              void* d_out, int out_size, void* d_ws, size_t ws_size,
                              hipStream_t stream) {
    const float* feat = (const float*)d_in[0];   // [64][1024][2048]
    const float* hs   = (const float*)d_in[1];   // [64][512]
    const float* W1   = (const float*)d_in[2];   // [2048][512]
    const float* b1   = (const float*)d_in[3];   // [512]
    const float* W2   = (const float*)d_in[4];   // [512][512]
    const float* b2   = (const float*)d_in[5];   // [512]
    const float* V    = (const float*)d_in[6];   // [512]
    // d_in[7] = bv: cancels in softmax, score not an output -> unused

    const size_t OFF_PH    = 2u * 1024 * 1024;
    const size_t OFF_SCORE = OFF_PH + 128u * 1024;
    const size_t OFF_PART  = OFF_SCORE + 256u * 1024;
    const size_t NEED_PART = OFF_PART + (size_t)64 * 8 * 2048 * 4;

    unsigned short* w1t = (unsigned short*)d_ws;
    float* ph    = (float*)((char*)d_ws + OFF_PH);
    float* score = (float*)((char*)d_ws + OFF_SCORE);
    float* part  = (float*)((char*)d_ws + OFF_PART);

    float* ctx  = (float*)d_out;          // [64][2048]
    float* wout = ctx + 64 * 2048;        // [64][1024][1]

    const int use_part = (ws_size >= NEED_PART) ? 1 : 0;

    k_w1t    <<<dim3(32, 8), 256, 0, stream>>>(W1, w1t);
    k_projh  <<<dim3(64, 4), 256, 0, stream>>>(hs, W2, b2, ph);
    k_score  <<<1024,        256, 0, stream>>>(feat, w1t, b1, ph, V, score);
    k_softmax<<<64,          256, 0, stream>>>(score, wout, ctx, use_part ? 0 : 1);
    if (use_part) {
        k_ctx_part<<<dim3(64, 8), 256, 0, stream>>>(feat, wout, part);
        k_ctx_red <<<64,          256, 0, stream>>>(part, ctx);
    } else {
        k_ctx_atomic<<<dim3(64, 8), 256, 0, stream>>>(feat, wout, ctx);
    }
}